// Round 3
// baseline (241.251 us; speedup 1.0000x reference)
//
#include <hip/hip_runtime.h>
#include <math.h>

#define E     128
#define NEXP  8
#define HDIM  512
#define NCLS  1000
#define NB    128
#define EPS   1e-5f

__device__ __forceinline__ float block_sum128(float v, float* red, int tid) {
    red[tid] = v;
    __syncthreads();
    for (int s = 64; s > 0; s >>= 1) {
        if (tid < s) red[tid] += red[tid + s];
        __syncthreads();
    }
    float r = red[0];
    __syncthreads();
    return r;
}

// One block of 128 threads computes the full CLS-token pipeline -> logits[1000]
__global__ __launch_bounds__(128) void vitmoe_cls_logits(
    const float* __restrict__ cls_token,   // [E]
    const float* __restrict__ pos_embed,   // [N*E] (token 0 = first E)
    const float* __restrict__ router_w,    // [NEXP*E]
    const float* __restrict__ router_b,    // [NEXP]
    const float* __restrict__ ln1_g, const float* __restrict__ ln1_b,   // [NEXP*E]
    const float* __restrict__ wv,    const float* __restrict__ bv,      // [NEXP*E*E],[NEXP*E]
    const float* __restrict__ wo,    const float* __restrict__ bo,      // [NEXP*E*E],[NEXP*E]
    const float* __restrict__ ln2_g, const float* __restrict__ ln2_b,   // [NEXP*E]
    const float* __restrict__ w1,    const float* __restrict__ b1,      // [NEXP*E*H],[NEXP*H]
    const float* __restrict__ w2,    const float* __restrict__ b2,      // [NEXP*H*E],[NEXP*E]
    const float* __restrict__ norm_g, const float* __restrict__ norm_b, // [E]
    const float* __restrict__ head_w, const float* __restrict__ head_b, // [NCLS*E],[NCLS]
    float* __restrict__ logits)            // [NCLS] (workspace)
{
    __shared__ float t0[E], xn[E], buf[E], av[E], hn[E], mh[HDIM], moe[E], z[E];
    __shared__ float red[E];
    __shared__ int   sel[2];
    const int tid = threadIdx.x;

    // t0 = cls_token + pos_embed[token 0]  (batch-independent, x-independent)
    t0[tid] = cls_token[tid] + pos_embed[tid];
    __syncthreads();

    // Router top-2 (softmax is monotonic -> top-k on raw logits; strict '>' scan
    // from index 0 matches jax.lax.top_k tie-breaking, lower index wins)
    if (tid == 0) {
        float l[NEXP];
        for (int x = 0; x < NEXP; ++x) {
            float s = router_b[x];
            for (int e = 0; e < E; ++e) s += t0[e] * router_w[x * E + e];
            l[x] = s;
        }
        int b0 = 0;
        for (int x = 1; x < NEXP; ++x) if (l[x] > l[b0]) b0 = x;
        int b1i = -1;
        for (int x = 0; x < NEXP; ++x) {
            if (x == b0) continue;
            if (b1i < 0 || l[x] > l[b1i]) b1i = x;
        }
        sel[0] = b0; sel[1] = b1i;
    }

    // Shared LN stats of t0 (gamma/beta applied per-expert later)
    {
        float m = block_sum128(t0[tid], red, tid) * (1.0f / E);
        float d = t0[tid] - m;
        float v = block_sum128(d * d, red, tid) * (1.0f / E);
        xn[tid] = d * rsqrtf(v + EPS);
    }
    __syncthreads();   // also guarantees sel[] is visible

    moe[tid] = 0.0f;
    __syncthreads();

    for (int kk = 0; kk < 2; ++kk) {
        const int x = sel[kk];
        // y = xn * ln1_g + ln1_b
        buf[tid] = xn[tid] * ln1_g[x * E + tid] + ln1_b[x * E + tid];
        __syncthreads();
        // a[f] = dot(y, wv[x][f,:]) + bv[x][f]   (torch Linear: [out,in])
        {
            float s = bv[x * E + tid];
            const float* wrow = wv + ((size_t)x * E + tid) * E;
            for (int e = 0; e < E; ++e) s += buf[e] * wrow[e];
            av[tid] = s;
        }
        __syncthreads();
        // a2[g] = dot(a, wo[x][g,:]) + bo[x][g];  h = t0 + a2
        float hv;
        {
            float s = bo[x * E + tid];
            const float* wrow = wo + ((size_t)x * E + tid) * E;
            for (int f = 0; f < E; ++f) s += av[f] * wrow[f];
            hv = t0[tid] + s;
        }
        __syncthreads();
        // hn = LN(h) with ln2 params
        {
            float m2 = block_sum128(hv, red, tid) * (1.0f / E);
            float d2 = hv - m2;
            float v2 = block_sum128(d2 * d2, red, tid) * (1.0f / E);
            hn[tid] = d2 * rsqrtf(v2 + EPS) * ln2_g[x * E + tid] + ln2_b[x * E + tid];
        }
        __syncthreads();
        // mh[j] = gelu_exact(dot(hn, w1[x][:,j]) + b1[x][j]); w1 is [E,H] -> stride H over e
        for (int r = 0; r < HDIM / E; ++r) {
            const int j = tid + r * E;
            float s1 = b1[x * HDIM + j];
            const float* w1p = w1 + (size_t)x * E * HDIM + j;
            for (int e = 0; e < E; ++e) s1 += hn[e] * w1p[e * HDIM];
            mh[j] = 0.5f * s1 * (1.0f + erff(s1 * 0.70710678118654752f));
        }
        __syncthreads();
        // out[e] = h[e] + dot(mh, w2[x][:,e]) + b2[x][e]; w2 is [H,E] -> stride E over j
        {
            float o = hv + b2[x * E + tid];
            const float* w2p = w2 + (size_t)x * HDIM * E + tid;
            for (int j = 0; j < HDIM; ++j) o += mh[j] * w2p[j * E];
            moe[tid] += 0.5f * o;   // unweighted mean over K=2
        }
        __syncthreads();
    }

    // Final LN
    {
        float mo = moe[tid];
        float m3 = block_sum128(mo, red, tid) * (1.0f / E);
        float d3 = mo - m3;
        float v3 = block_sum128(d3 * d3, red, tid) * (1.0f / E);
        z[tid] = d3 * rsqrtf(v3 + EPS) * norm_g[tid] + norm_b[tid];
    }
    __syncthreads();

    // Head: logits[c] = dot(z, head_w[c,:]) + head_b[c]
    for (int c = tid; c < NCLS; c += E) {
        float s = head_b[c];
        const float* hw = head_w + (size_t)c * E;
        for (int e = 0; e < E; ++e) s += z[e] * hw[e];
        logits[c] = s;
    }
}

// Broadcast logits[1000] to out[128,1000]
__global__ __launch_bounds__(256) void vitmoe_broadcast(
    const float* __restrict__ logits, float* __restrict__ out)
{
    const int c = blockIdx.x * 256 + threadIdx.x;
    const int b = blockIdx.y;
    if (c < NCLS) out[(size_t)b * NCLS + c] = logits[c];
}

extern "C" void kernel_launch(void* const* d_in, const int* in_sizes, int n_in,
                              void* d_out, int out_size, void* d_ws, size_t ws_size,
                              hipStream_t stream) {
    // setup_inputs() order:
    // 0 x, 1 conv_w, 2 conv_b, 3 cls_token, 4 pos_embed, 5 router_w, 6 router_b,
    // 7 ln1_g, 8 ln1_b, 9 wv, 10 bv, 11 wo, 12 bo, 13 ln2_g, 14 ln2_b,
    // 15 w1, 16 b1, 17 w2, 18 b2, 19 norm_g, 20 norm_b, 21 head_w, 22 head_b
    const float* cls_token = (const float*)d_in[3];
    const float* pos_embed = (const float*)d_in[4];
    const float* router_w  = (const float*)d_in[5];
    const float* router_b  = (const float*)d_in[6];
    const float* ln1_g     = (const float*)d_in[7];
    const float* ln1_b     = (const float*)d_in[8];
    const float* wv        = (const float*)d_in[9];
    const float* bv        = (const float*)d_in[10];
    const float* wo        = (const float*)d_in[11];
    const float* bo        = (const float*)d_in[12];
    const float* ln2_g     = (const float*)d_in[13];
    const float* ln2_b     = (const float*)d_in[14];
    const float* w1        = (const float*)d_in[15];
    const float* b1        = (const float*)d_in[16];
    const float* w2        = (const float*)d_in[17];
    const float* b2        = (const float*)d_in[18];
    const float* norm_g    = (const float*)d_in[19];
    const float* norm_b    = (const float*)d_in[20];
    const float* head_w    = (const float*)d_in[21];
    const float* head_b    = (const float*)d_in[22];

    float* logits = (float*)d_ws;          // 1000 floats of scratch
    float* out    = (float*)d_out;         // [128,1000] fp32

    vitmoe_cls_logits<<<1, 128, 0, stream>>>(
        cls_token, pos_embed, router_w, router_b,
        ln1_g, ln1_b, wv, bv, wo, bo, ln2_g, ln2_b,
        w1, b1, w2, b2, norm_g, norm_b, head_w, head_b, logits);

    dim3 grid((NCLS + 255) / 256, NB);
    vitmoe_broadcast<<<grid, 256, 0, stream>>>(logits, out);
}

// Round 4
// 178.745 us; speedup vs baseline: 1.3497x; 1.3497x over previous
//
#include <hip/hip_runtime.h>
#include <math.h>

#define E     128
#define NEXP  8
#define HDIM  512
#define NCLS  1000
#define NB    128
#define EPS   1e-5f

// ---- workspace layout (floats) ----
// 0    : t0[128]
// 128  : xn[128]
// 256  : y[2][128]
// 512  : a[2][128]
// 768  : hn[2][128]
// 1024 : moe_part[2][128]   (init by K3, atomicAdd by K5)
// 1280 : mh[2][512]
// 2304 : z[128]
// 2432 : sel[2] (ints, reinterpreted)
#define WS_T0   0
#define WS_XN   128
#define WS_Y    256
#define WS_A    512
#define WS_HN   768
#define WS_MP   1024
#define WS_MH   1280
#define WS_Z    2304
#define WS_SEL  2432

__device__ __forceinline__ float wave_red64(float v) {
    for (int off = 32; off > 0; off >>= 1) v += __shfl_down(v, off, 64);
    return v;
}

// K1: t0, router top-2, shared LN stats, per-expert pre-LN scale (1 block, 128 thr)
__global__ __launch_bounds__(128) void k1_prep(
    const float* __restrict__ cls_token, const float* __restrict__ pos_embed,
    const float* __restrict__ router_w,  const float* __restrict__ router_b,
    const float* __restrict__ ln1_g,     const float* __restrict__ ln1_b,
    float* __restrict__ ws)
{
    __shared__ float t0s[E], red[E], lg[NEXP];
    __shared__ int sel[2];
    const int tid = threadIdx.x;

    float t0 = cls_token[tid] + pos_embed[tid];
    t0s[tid] = t0;
    ws[WS_T0 + tid] = t0;
    __syncthreads();

    // router logits: 8 experts x 16-thread groups of 8 elems
    {
        const int x = tid >> 4, i = tid & 15;
        float s = 0.f;
        const float* rw = router_w + x * E + i * 8;
        const float* t8 = t0s + i * 8;
        #pragma unroll
        for (int e = 0; e < 8; ++e) s += t8[e] * rw[e];
        red[tid] = s;
    }
    __syncthreads();
    if (tid < NEXP) {
        float s = router_b[tid];
        for (int i = 0; i < 16; ++i) s += red[tid * 16 + i];
        lg[tid] = s;
    }
    __syncthreads();
    if (tid == 0) {
        int b0 = 0;
        for (int x = 1; x < NEXP; ++x) if (lg[x] > lg[b0]) b0 = x;
        int b1i = -1;
        for (int x = 0; x < NEXP; ++x) {
            if (x == b0) continue;
            if (b1i < 0 || lg[x] > lg[b1i]) b1i = x;
        }
        sel[0] = b0; sel[1] = b1i;
        ((int*)(ws + WS_SEL))[0] = b0;
        ((int*)(ws + WS_SEL))[1] = b1i;
    }

    // shared LN stats of t0
    red[tid] = t0; __syncthreads();
    for (int s = 64; s > 0; s >>= 1) { if (tid < s) red[tid] += red[tid + s]; __syncthreads(); }
    float m = red[0] * (1.f / E); __syncthreads();
    float d = t0 - m;
    red[tid] = d * d; __syncthreads();
    for (int s = 64; s > 0; s >>= 1) { if (tid < s) red[tid] += red[tid + s]; __syncthreads(); }
    float xn = d * rsqrtf(red[0] * (1.f / E) + EPS);
    ws[WS_XN + tid] = xn;
    __syncthreads();

    for (int kk = 0; kk < 2; ++kk) {
        const int x = sel[kk];
        ws[WS_Y + kk * E + tid] = xn * ln1_g[x * E + tid] + ln1_b[x * E + tid];
    }
}

// K2: a[kk][f] = dot(y[kk], wv[x][f,:]) + bv[x][f] — wave per row, 64 blocks x 256 thr
__global__ __launch_bounds__(256) void k2_vproj(
    const float* __restrict__ wv, const float* __restrict__ bv, float* __restrict__ ws)
{
    const int tid = threadIdx.x, lane = tid & 63, w = tid >> 6;
    const int r = blockIdx.x * 4 + w;          // 0..255
    const int kk = r >> 7, f = r & 127;
    const int x = ((const int*)(ws + WS_SEL))[kk];
    const float* row = wv + ((size_t)x * E + f) * E;
    float s = ws[WS_Y + kk * E + lane] * row[lane]
            + ws[WS_Y + kk * E + 64 + lane] * row[64 + lane];
    s = wave_red64(s);
    if (lane == 0) ws[WS_A + kk * E + f] = s + bv[x * E + f];
}

// K3: per-expert o-proj + residual + LN2 -> hn; init moe_part = 0.5*(h+b2). 2 blocks x 512 thr
__global__ __launch_bounds__(512) void k3_oproj_ln(
    const float* __restrict__ wo, const float* __restrict__ bo,
    const float* __restrict__ ln2_g, const float* __restrict__ ln2_b,
    const float* __restrict__ b2, float* __restrict__ ws)
{
    __shared__ float avs[E], hs[E], red[E];
    const int tid = threadIdx.x, lane = tid & 63, w = tid >> 6;  // 8 waves
    const int kk = blockIdx.x;
    const int x = ((const int*)(ws + WS_SEL))[kk];

    if (tid < E) avs[tid] = ws[WS_A + kk * E + tid];
    __syncthreads();

    for (int g16 = 0; g16 < 16; ++g16) {
        const int g = w * 16 + g16;
        const float* row = wo + ((size_t)x * E + g) * E;
        float s = avs[lane] * row[lane] + avs[64 + lane] * row[64 + lane];
        s = wave_red64(s);
        if (lane == 0) hs[g] = ws[WS_T0 + g] + s + bo[x * E + g];
    }
    __syncthreads();

    // LN over hs (threads 0..127 compute, all sync)
    float hv = (tid < E) ? hs[tid] : 0.f;
    if (tid < E) red[tid] = hv;
    __syncthreads();
    for (int s = 64; s > 0; s >>= 1) { if (tid < s) red[tid] += red[tid + s]; __syncthreads(); }
    float m = red[0] * (1.f / E); __syncthreads();
    float d = hv - m;
    if (tid < E) red[tid] = d * d;
    __syncthreads();
    for (int s = 64; s > 0; s >>= 1) { if (tid < s) red[tid] += red[tid + s]; __syncthreads(); }
    if (tid < E) {
        float hn = d * rsqrtf(red[0] * (1.f / E) + EPS) * ln2_g[x * E + tid] + ln2_b[x * E + tid];
        ws[WS_HN + kk * E + tid] = hn;
        ws[WS_MP + kk * E + tid] = 0.5f * (hv + b2[x * E + tid]);
    }
}

// K4: mh[kk][j] = gelu(dot(hn[kk], w1[x][:,j]) + b1[x][j]) — grid (2,4), 128 thr
__global__ __launch_bounds__(128) void k4_mlp1(
    const float* __restrict__ w1, const float* __restrict__ b1, float* __restrict__ ws)
{
    __shared__ float hns[E];
    const int tid = threadIdx.x;
    const int kk = blockIdx.x, jc = blockIdx.y;
    const int x = ((const int*)(ws + WS_SEL))[kk];
    hns[tid] = ws[WS_HN + kk * E + tid];
    __syncthreads();

    const int j = jc * 128 + tid;
    const float* base = w1 + (size_t)x * E * HDIM + j;
    float s = b1[x * HDIM + j];
    #pragma unroll 8
    for (int e = 0; e < E; ++e) s += hns[e] * base[(size_t)e * HDIM];
    ws[WS_MH + kk * HDIM + j] = 0.5f * s * (1.0f + erff(s * 0.70710678118654752f));
}

// K5: moe_part[kk][e] += 0.5 * sum_{j in chunk} mh[kk][j]*w2[x][j][e] — grid (2,4), 128 thr
__global__ __launch_bounds__(128) void k5_mlp2(
    const float* __restrict__ w2, float* __restrict__ ws)
{
    __shared__ float mhs[128];
    const int tid = threadIdx.x;
    const int kk = blockIdx.x, jc = blockIdx.y;
    const int x = ((const int*)(ws + WS_SEL))[kk];
    mhs[tid] = ws[WS_MH + kk * HDIM + jc * 128 + tid];
    __syncthreads();

    const float* base = w2 + (size_t)x * HDIM * E + (size_t)jc * 128 * E + tid;
    float s = 0.f;
    #pragma unroll 8
    for (int jj = 0; jj < 128; ++jj) s += mhs[jj] * base[(size_t)jj * E];
    atomicAdd(&ws[WS_MP + kk * E + tid], 0.5f * s);
}

// K6: moe = mp[0]+mp[1]; z = LN(moe)*g+b — 1 block, 128 thr
__global__ __launch_bounds__(128) void k6_finalln(
    const float* __restrict__ norm_g, const float* __restrict__ norm_b, float* __restrict__ ws)
{
    __shared__ float red[E];
    const int tid = threadIdx.x;
    float mo = ws[WS_MP + tid] + ws[WS_MP + E + tid];
    red[tid] = mo; __syncthreads();
    for (int s = 64; s > 0; s >>= 1) { if (tid < s) red[tid] += red[tid + s]; __syncthreads(); }
    float m = red[0] * (1.f / E); __syncthreads();
    float d = mo - m;
    red[tid] = d * d; __syncthreads();
    for (int s = 64; s > 0; s >>= 1) { if (tid < s) red[tid] += red[tid + s]; __syncthreads(); }
    ws[WS_Z + tid] = d * rsqrtf(red[0] * (1.f / E) + EPS) * norm_g[tid] + norm_b[tid];
}

// K7: logits c=4*blk..4*blk+3 via wave-per-row, then broadcast to out[128][1000] as float4.
// 250 blocks x 256 thr. (1000 = 4*250; 4000B row stride ≡ 0 mod 16 -> aligned float4)
__global__ __launch_bounds__(256) void k7_head_bcast(
    const float* __restrict__ head_w, const float* __restrict__ head_b,
    const float* __restrict__ ws, float* __restrict__ out)
{
    __shared__ float lg[4];
    const int tid = threadIdx.x, lane = tid & 63, w = tid >> 6;
    const int c = blockIdx.x * 4 + w;
    const float* row = head_w + (size_t)c * E;
    float s = ws[WS_Z + lane] * row[lane] + ws[WS_Z + 64 + lane] * row[64 + lane];
    s = wave_red64(s);
    if (lane == 0) lg[w] = s + head_b[c];
    __syncthreads();
    if (tid < NB) {
        float4 v = *(const float4*)lg;
        *(float4*)(out + (size_t)tid * NCLS + blockIdx.x * 4) = v;
    }
}

extern "C" void kernel_launch(void* const* d_in, const int* in_sizes, int n_in,
                              void* d_out, int out_size, void* d_ws, size_t ws_size,
                              hipStream_t stream) {
    // 0 x, 1 conv_w, 2 conv_b, 3 cls_token, 4 pos_embed, 5 router_w, 6 router_b,
    // 7 ln1_g, 8 ln1_b, 9 wv, 10 bv, 11 wo, 12 bo, 13 ln2_g, 14 ln2_b,
    // 15 w1, 16 b1, 17 w2, 18 b2, 19 norm_g, 20 norm_b, 21 head_w, 22 head_b
    const float* cls_token = (const float*)d_in[3];
    const float* pos_embed = (const float*)d_in[4];
    const float* router_w  = (const float*)d_in[5];
    const float* router_b  = (const float*)d_in[6];
    const float* ln1_g     = (const float*)d_in[7];
    const float* ln1_b     = (const float*)d_in[8];
    const float* wv        = (const float*)d_in[9];
    const float* bv        = (const float*)d_in[10];
    const float* wo        = (const float*)d_in[11];
    const float* bo        = (const float*)d_in[12];
    const float* ln2_g     = (const float*)d_in[13];
    const float* ln2_b     = (const float*)d_in[14];
    const float* w1        = (const float*)d_in[15];
    const float* b1        = (const float*)d_in[16];
    const float* w2        = (const float*)d_in[17];
    const float* b2        = (const float*)d_in[18];
    const float* norm_g    = (const float*)d_in[19];
    const float* norm_b    = (const float*)d_in[20];
    const float* head_w    = (const float*)d_in[21];
    const float* head_b    = (const float*)d_in[22];

    float* ws  = (float*)d_ws;
    float* out = (float*)d_out;

    k1_prep<<<1, 128, 0, stream>>>(cls_token, pos_embed, router_w, router_b, ln1_g, ln1_b, ws);
    k2_vproj<<<64, 256, 0, stream>>>(wv, bv, ws);
    k3_oproj_ln<<<2, 512, 0, stream>>>(wo, bo, ln2_g, ln2_b, b2, ws);
    k4_mlp1<<<dim3(2, 4), 128, 0, stream>>>(w1, b1, ws);
    k5_mlp2<<<dim3(2, 4), 128, 0, stream>>>(w2, ws);
    k6_finalln<<<1, 128, 0, stream>>>(norm_g, norm_b, ws);
    k7_head_bcast<<<250, 256, 0, stream>>>(head_w, head_b, ws, out);
}